// Round 11
// baseline (324.455 us; speedup 1.0000x reference)
//
#include <hip/hip_runtime.h>
#include <stdint.h>

// LinearConv2D: y[b, o=g*8+n, fi, t] =
//   sum_{d<8, fr<2, w<16} x[b, g*8+d, 2*fi+fr, 4*t+w] * wt[g*8+n, d, 2*fi+fr, w]
// Shapes: x[16,64,128,256] f32, wt[64,8,128,16] f32, out[16,64,64,61] f32.
//
// R18: R16 (verified: dur 197.8, kernel ~37us) with barriers halved 16->8.
// Rule (2-for-2 correlation): kernels with asm s_waitcnt in the loop kill
// the container (R14, R17); asm-free kernels run. So: barrier-gated only.
// Accounting of R16's 37us: LDS-port floor ~31us (8 waves/CU x 16 steps x
// 48 b128 x 12cy) + ~5-6us of 16 per-block barrier drains. Weight-broadcast
// traffic (20us/CU) is structural for Sb=4 (4 waves need the same weights;
// no cross-wave register sharing exists). Lever: the (d,fr=0/1) x rows are
// CONTIGUOUS 1KB rows -> stage 2KB/b per d-superstep:
//  - xlds[2][16][128]: 64KB dbuf + 8KB weights = 72KB -> 2 blocks/CU.
//  - 8 supersteps, 8 __syncthreads (each wave stages/reads only its own 4
//    b-rows; the barrier is a self-drain - cross-wave safety unchanged).
//  - each barrier now amortized over 1024 FMAs (2048cy) vs 512.
//  - swizzle/DMA/weight machinery identical to R16 (verified).
// Predicted: passes; LDS 73728, VGPR 90-110, conflicts ~0, WRITE_SIZE ~17MB
// (spill tripwire); kernel 31-34us; dur 192-195.
// Falsifier: dur >= 197 -> barrier share overestimated, kernel at LDS-port
// floor; remaining lever (8b/wave @ 4 waves/CU) likely regresses -> ceiling.

namespace {
constexpr int kC  = 64;
constexpr int kF  = 128;
constexpr int kT  = 256;
constexpr int kD  = 8;
constexpr int kN  = 8;
constexpr int kW  = 16;
constexpr int kNT = 61;   // (256-16)/4 + 1
constexpr int kO  = 64;
constexpr int kFP = 64;   // (128-2)/2 + 1
constexpr int kWStride = kD * kF * kW;  // 16384: per-n weight stride (floats)
}

typedef float f32x4 __attribute__((ext_vector_type(4)));

// Async global->LDS, 16B/lane: writes ldsdst + lane*16 from per-lane gsrc.
__device__ __forceinline__ void gload_lds16(const float* gsrc, float* ldsdst) {
  __builtin_amdgcn_global_load_lds(
      (const __attribute__((address_space(1))) uint32_t*)gsrc,
      (__attribute__((address_space(3))) uint32_t*)ldsdst, 16, 0, 0);
}

__global__ __launch_bounds__(256, 2)
void lc2d_kernel(const float* __restrict__ x,
                 const float* __restrict__ wt,
                 float* __restrict__ out) {
  __shared__ f32x4 wlds[512];           // 8 KB: weight slice for (g,fi)
  __shared__ f32x4 xlds[2][16][128];    // 64 KB: x dbuf [buf][b][fr*64+slot]

  const int tid  = threadIdx.x;
  const int lane = tid & 63;
  const int wq   = tid >> 6;     // wave -> b-quad
  const int fi   = blockIdx.x;   // 0..63
  const int g    = blockIdx.y;   // 0..7

  // ---- Stage weights -> LDS (once; coalesced in 128B runs of 8 threads) ---
  // Layout: quad q = n*64 + (d*2+fr)*4 + qq.
  {
    const float* wb = wt + ((size_t)(g * kN) * kD * kF + (size_t)fi * 2) * kW;
#pragma unroll
    for (int r = 0; r < 2; ++r) {
      const int q  = tid + r * 256;
      const int n  = q >> 6;
      const int dd = (q >> 3) & 7;
      const int fr = (q >> 2) & 1;
      const int qq = q & 3;
      wlds[q] = *(const f32x4*)(wb + (size_t)n * kWStride + dd * (kF * kW) +
                                fr * kW + qq * 4);
    }
  }

  // x row bases for this wave's 4 b.
  const float* xrow[4];
#pragma unroll
  for (int bb = 0; bb < 4; ++bb) {
    const int b = wq * 4 + bb;
    xrow[bb] = x + ((size_t)(b * kC + g * kD) * kF + fi * 2) * kT;
  }

  // Staging source pre-swizzle (m173): LDS slot l receives global quad
  // pinv(l), so slot p(q) holds quad q. p(q)=(q&56)|((q+(q>>3))&7).
  const int pinv = (lane & 56) | ((lane - (lane >> 3)) & 7);

  // Window read byte-offsets: lane t reads quads t..t+3 at slots p(t+j).
  const int tcl = (lane < kNT) ? lane : (kNT - 1);   // clamp -> q <= 63
  int pj[4];
#pragma unroll
  for (int j = 0; j < 4; ++j) {
    const int q = tcl + j;
    pj[j] = ((q & 56) | ((q + (q >> 3)) & 7)) << 4;   // byte offset in row
  }
  const char* xbase = (const char*)&xlds[0][0][0];

  float acc[4][kN];
#pragma unroll
  for (int bb = 0; bb < 4; ++bb)
#pragma unroll
    for (int n = 0; n < kN; ++n) acc[bb][n] = 0.f;

  // Prologue: stage superstep d=0 (rows fr=0,1 contiguous; 2KB/b) -> buf 0.
#pragma unroll
  for (int bb = 0; bb < 4; ++bb) {
    gload_lds16(xrow[bb] + 4 * pinv,      (float*)&xlds[0][wq * 4 + bb][0]);
    gload_lds16(xrow[bb] + kT + 4 * pinv, (float*)&xlds[0][wq * 4 + bb][64]);
  }

#pragma unroll 2
  for (int d = 0; d < 8; ++d) {
    const int cur = d & 1;
    __syncthreads();   // own DMAs for buf cur drained (vmcnt0+lgkm0)

    if (d < 7) {       // stage superstep d+1 into the other buffer (async)
      const float* rb0 = xrow[0] + (size_t)(d + 1) * (kF * kT);
#pragma unroll
      for (int bb = 0; bb < 4; ++bb) {
        const float* rb = xrow[bb] + (size_t)(d + 1) * (kF * kT);
        gload_lds16(rb + 4 * pinv,
                    (float*)&xlds[cur ^ 1][wq * 4 + bb][0]);
        gload_lds16(rb + kT + 4 * pinv,
                    (float*)&xlds[cur ^ 1][wq * 4 + bb][64]);
      }
      (void)rb0;
    }

    // Compute both fr halves of superstep d from buf cur.
#pragma unroll
    for (int fr = 0; fr < 2; ++fr) {
      const int qb = d * 8 + fr * 4;   // weight quad base for (d,fr)
      f32x4 xq[4][4];
#pragma unroll
      for (int bb = 0; bb < 4; ++bb) {
        const char* rb =
            xbase + cur * 32768 + (wq * 4 + bb) * 2048 + fr * 1024;
#pragma unroll
        for (int j = 0; j < 4; ++j)
          xq[bb][j] = *(const f32x4*)(rb + pj[j]);
      }
#pragma unroll
      for (int n = 0; n < kN; ++n) {
        const f32x4 w0 = wlds[n * 64 + qb + 0];
        const f32x4 w1 = wlds[n * 64 + qb + 1];
        const f32x4 w2 = wlds[n * 64 + qb + 2];
        const f32x4 w3 = wlds[n * 64 + qb + 3];
#pragma unroll
        for (int bb = 0; bb < 4; ++bb) {
          float a = acc[bb][n];
          a = fmaf(xq[bb][0].x, w0.x, a);
          a = fmaf(xq[bb][0].y, w0.y, a);
          a = fmaf(xq[bb][0].z, w0.z, a);
          a = fmaf(xq[bb][0].w, w0.w, a);
          a = fmaf(xq[bb][1].x, w1.x, a);
          a = fmaf(xq[bb][1].y, w1.y, a);
          a = fmaf(xq[bb][1].z, w1.z, a);
          a = fmaf(xq[bb][1].w, w1.w, a);
          a = fmaf(xq[bb][2].x, w2.x, a);
          a = fmaf(xq[bb][2].y, w2.y, a);
          a = fmaf(xq[bb][2].z, w2.z, a);
          a = fmaf(xq[bb][2].w, w2.w, a);
          a = fmaf(xq[bb][3].x, w3.x, a);
          a = fmaf(xq[bb][3].y, w3.y, a);
          a = fmaf(xq[bb][3].z, w3.z, a);
          a = fmaf(xq[bb][3].w, w3.w, a);
          acc[bb][n] = a;
        }
      }
    }
  }

  if (lane < kNT) {
    const size_t s = (size_t)kFP * kNT;
#pragma unroll
    for (int bb = 0; bb < 4; ++bb) {
      const int b = wq * 4 + bb;
      float* ob =
          out + (((size_t)b * kO + g * kN) * kFP + fi) * (size_t)kNT + lane;
#pragma unroll
      for (int n = 0; n < kN; ++n) ob[(size_t)n * s] = acc[bb][n];
    }
  }
}

extern "C" void kernel_launch(void* const* d_in, const int* in_sizes, int n_in,
                              void* d_out, int out_size, void* d_ws, size_t ws_size,
                              hipStream_t stream) {
  const float* x  = (const float*)d_in[0];
  const float* wt = (const float*)d_in[1];
  float* out      = (float*)d_out;

  dim3 grid(kFP, 8, 1);   // 64 x 8 = 512 blocks of 256 threads (16 b inside)
  lc2d_kernel<<<grid, 256, 0, stream>>>(x, wt, out);
}